// Round 8
// baseline (192.351 us; speedup 1.0000x reference)
//
#include <hip/hip_runtime.h>
#include <hip/hip_bf16.h>
#include <cstdint>
#include <cstddef>

// Problem constants (B=4, N=256, D=32, H=512)
#define NB 4
#define NN 256
#define DD 32
#define HH 512

typedef __attribute__((ext_vector_type(8))) short short8;    // 8 bf16 (4 VGPRs) — MFMA A/B frag
typedef __attribute__((ext_vector_type(4))) float f32x4;     // 16x16 C/D frag
typedef __attribute__((ext_vector_type(16))) float f32x16;   // 32x32 C/D frag

// HW packed fp32->bf16 (RNE). a -> low 16, b -> high 16.
static __device__ __forceinline__ unsigned cvtpk(float a, float b) {
  unsigned r;
  asm("v_cvt_pk_bf16_f32 %0, %1, %2" : "=v"(r) : "v"(a), "v"(b));
  return r;
}

// ---------------------------------------------------------------------------
// prep_all (grid 384x256): three regions by thread id.
//  A: t in [0,16384):     zbf (bf16 copy of z), one float2 -> uint each
//                         (16384 float2 = all 32768 z elements)
//  B: t in [16384,32768): W2F — W2 (512x256) in 32x32x16 MFMA B-frag order:
//       slot f8 = w*4096 + hc*512 + s*128 + nt*64 + lane (uint4 of 8 bf16)
//       h = hc*64+s*16+(lane>>5)*8+e ; k2 = w*64+nt*32+(lane&31)
//  C: t in [32768,98304): W1F — W1 in 16x16x32 B-frag order for prep_T2 with
//       column interleave n = nblk*256 + w*64 + l16*4 + nt  (so prep_T2 can
//       store 4 consecutive n per lane as one packed b64)
// ---------------------------------------------------------------------------
__global__ __launch_bounds__(256) void prep_all(const float* __restrict__ z,
                                                const float* __restrict__ W1,
                                                const float* __restrict__ W2,
                                                unsigned* __restrict__ zbf_u,
                                                unsigned short* __restrict__ W2F,
                                                unsigned short* __restrict__ W1F) {
  int t = blockIdx.x * 256 + threadIdx.x;
  if (t < 16384) {
    float2 v = ((const float2*)z)[t];
    zbf_u[t] = cvtpk(v.x, v.y);
  } else if (t < 32768) {
    int f8 = t - 16384;                   // frag-slot index (8 elems each)
    int lane = f8 & 63;
    int nt = (f8 >> 6) & 1, s = (f8 >> 7) & 3, hc = (f8 >> 9) & 7, w = (f8 >> 12) & 3;
    int k2 = w * 64 + nt * 32 + (lane & 31);
    int hb = hc * 64 + s * 16 + (lane >> 5) * 8;
    float v[8];
    #pragma unroll
    for (int e = 0; e < 8; ++e) v[e] = W2[(hb + e) * 256 + k2];
    uint4 p;
    p.x = cvtpk(v[0], v[1]); p.y = cvtpk(v[2], v[3]);
    p.z = cvtpk(v[4], v[5]); p.w = cvtpk(v[6], v[7]);
    ((uint4*)W2F)[f8] = p;
  } else {
    int g = t - 32768;                    // [0, 65536) uint4 slots
    int lane = g & 63;
    int fragidx = g >> 6;                 // (nblk*16 + w*4 + nt)
    int nt = fragidx & 3, w = (fragidx >> 2) & 3, nblk = fragidx >> 4;
    int l16 = lane & 15, quad = lane >> 4;
    int n = nblk * 256 + w * 64 + l16 * 4 + nt;   // n = h*32 + c
    int c = n & 31, h = n >> 5;
    float v[8];
    #pragma unroll
    for (int e = 0; e < 8; ++e) {
      int a = quad * 8 + e;
      v[e] = W1[(a * 32 + c) * 512 + h];
    }
    uint4 p;
    p.x = cvtpk(v[0], v[1]); p.y = cvtpk(v[2], v[3]);
    p.z = cvtpk(v[4], v[5]); p.w = cvtpk(v[6], v[7]);
    ((uint4*)W1F)[g] = p;
  }
}

// ---------------------------------------------------------------------------
// prep_T2: Tall[bi][n] = sum_a z[bi][a] * W1p[a][n]  as MFMA GEMM (16x16x32)
// Column interleave n = ncol + l16*4 + nt -> each lane stores 4 consecutive
// n per (mt,r) as one packed b64 (16 b64 stores/lane vs 64 b16 before).
// ---------------------------------------------------------------------------
__global__ __launch_bounds__(256) void prep_T2(const unsigned short* __restrict__ zbf,
                                               const unsigned short* __restrict__ W1F,
                                               unsigned short* __restrict__ Tall) {
  const int tid = threadIdx.x;
  const int w = tid >> 6, lane = tid & 63;
  const int quad = lane >> 4, l16 = lane & 15;
  const int nblk = blockIdx.x, mblk = blockIdx.y;
  const int bibase = mblk * 64;

  short8 afr[4], bfr[4];
  #pragma unroll
  for (int mt = 0; mt < 4; ++mt)
    afr[mt] = *(const short8*)(zbf + (size_t)(bibase + mt * 16 + l16) * 32 + quad * 8);
  #pragma unroll
  for (int nt = 0; nt < 4; ++nt)
    bfr[nt] = *(const short8*)(W1F + (size_t)(nblk * 16 + w * 4 + nt) * 512 + lane * 8);

  f32x4 d[4][4];
  #pragma unroll
  for (int mt = 0; mt < 4; ++mt)
    #pragma unroll
    for (int nt = 0; nt < 4; ++nt)
      d[mt][nt] = __builtin_amdgcn_mfma_f32_16x16x32_bf16(
          afr[mt], bfr[nt], (f32x4){0.f, 0.f, 0.f, 0.f}, 0, 0, 0);

  const int n0 = nblk * 256 + w * 64 + l16 * 4;
  #pragma unroll
  for (int mt = 0; mt < 4; ++mt)
    #pragma unroll
    for (int r = 0; r < 4; ++r) {
      size_t rowoff = (size_t)(bibase + mt * 16 + quad * 4 + r) * 16384;
      uint2 p;
      p.x = cvtpk(d[mt][0][r], d[mt][1][r]);
      p.y = cvtpk(d[mt][2][r], d[mt][3][r]);
      *(uint2*)&Tall[rowoff + n0] = p;
    }
}

// ---------------------------------------------------------------------------
// fused: block = (b,i,jt of 64 j), 512 threads / 8 waves. Wave (jh,w):
//   jh = wave>>2 selects j-half (32 j), w = wave&3 selects k2 range [64w,+64).
//   acc = 2 x f32x16 = 32 AGPRs/wave -> ~4-5 waves/SIMD co-resident.
// H split into 2 halves of 256:
//   phase1: 8 waves each fill 2x16 h-rows x 64 j of h1s (16x16x32, b1 as C)
//   phase2: 16 u-steps, 2 MFMA 32x32x16 per wave per step, 1-deep pipelined
// ---------------------------------------------------------------------------
__global__ __launch_bounds__(512) void fused(const unsigned short* __restrict__ Tall,
                                             const unsigned short* __restrict__ W2F,
                                             const unsigned short* __restrict__ zbf,
                                             const float* __restrict__ b1,
                                             const float* __restrict__ b2,
                                             const float* __restrict__ W3,
                                             const float* __restrict__ b3,
                                             const float* __restrict__ motif,
                                             float* __restrict__ out) {
  __shared__ unsigned short h1s[64 * 264];   // [j][h_local], stride 264
  __shared__ float red[256];

  const int tid = threadIdx.x;
  const int w8 = tid >> 6, lane = tid & 63;
  const int quad = lane >> 4, l16 = lane & 15;
  const int L = lane >> 5, c32 = lane & 31;
  const int w = w8 & 3, jh = w8 >> 2;

  // XCD swizzle: 4 jt-siblings of one bi land on the same XCD (bx % 8 equal)
  const int bx = blockIdx.x;
  const int jt = (bx >> 3) & 3;
  const int bi = (bx & 7) | ((bx >> 5) << 3);   // b*256 + i
  const int b = bi >> 8, i = bi & 255;
  const int jbase = jt * 64;

  // phase-1 z frags (16x16x32 B-operand): [k=c=quad*8+e][n=j=l16]
  short8 zfr[4];
  #pragma unroll
  for (int nt = 0; nt < 4; ++nt)
    zfr[nt] = *(const short8*)(zbf + (size_t)(b * 256 + jbase + nt * 16 + l16) * 32 + quad * 8);

  // phase-1 T frags for both halves/q (hoisted; Tall is the cold stream)
  const unsigned short* Tbase = Tall + (size_t)bi * 16384 + (w8 * 16 + l16) * 32 + quad * 8;
  short8 tfr[2][2];
  #pragma unroll
  for (int half = 0; half < 2; ++half)
    #pragma unroll
    for (int q = 0; q < 2; ++q)
      tfr[half][q] = *(const short8*)(Tbase + half * 8192 + q * 4096);

  // epilogue constants: this wave owns k2 in [64w, 64w+64)
  float b2v[2], w3v[2];
  #pragma unroll
  for (int nt = 0; nt < 2; ++nt) {
    int k2 = w * 64 + nt * 32 + c32;
    b2v[nt] = b2[k2];
    w3v[nt] = W3[k2];
  }

  f32x16 acc[2];
  #pragma unroll
  for (int nt = 0; nt < 2; ++nt)
    acc[nt] = (f32x16){0.f,0.f,0.f,0.f,0.f,0.f,0.f,0.f,
                       0.f,0.f,0.f,0.f,0.f,0.f,0.f,0.f};

  const unsigned short* Wp = W2F + w * 32768 + lane * 8;
  const float* b1base = b1 + w8 * 16 + quad * 4;

  #pragma unroll
  for (int half = 0; half < 2; ++half) {
    // ---- phase 1: wave w8 fills h-rows {q*128 + w8*16 + [0,16)} x 64 j
    #pragma unroll
    for (int q = 0; q < 2; ++q) {
      float4 b1f = *(const float4*)(b1base + half * 256 + q * 128);
      f32x4 cin = {b1f.x, b1f.y, b1f.z, b1f.w};
      #pragma unroll
      for (int nt = 0; nt < 4; ++nt) {
        f32x4 d = __builtin_amdgcn_mfma_f32_16x16x32_bf16(tfr[half][q], zfr[nt], cin, 0, 0, 0);
        // D: row = quad*4+r -> h_rel, col = l16 -> j within nt's 16
        uint2 p;
        p.x = cvtpk(fmaxf(d[0], 0.f), fmaxf(d[1], 0.f));
        p.y = cvtpk(fmaxf(d[2], 0.f), fmaxf(d[3], 0.f));
        *(uint2*)&h1s[(nt * 16 + l16) * 264 + q * 128 + w8 * 16 + quad * 4] = p;
      }
    }
    __syncthreads();

    // ---- phase 2: 16 u-steps (h_local = u*16 + L*8), 1-deep pipelined
    const unsigned short* Wh = Wp + half * 16384;
    const unsigned short* h1r = &h1s[(jh * 32 + c32) * 264 + L * 8];
    short8 bfA[2][2], afA[2];
    bfA[0][0] = *(const short8*)(Wh);
    bfA[0][1] = *(const short8*)(Wh + 512);
    afA[0] = *(const short8*)(h1r);
    #pragma unroll
    for (int u = 0; u < 16; ++u) {
      const int cur = u & 1, nxt = cur ^ 1;
      if (u < 15) {
        bfA[nxt][0] = *(const short8*)(Wh + (u + 1) * 1024);
        bfA[nxt][1] = *(const short8*)(Wh + (u + 1) * 1024 + 512);
        afA[nxt] = *(const short8*)(h1r + (u + 1) * 16);
      }
      acc[0] = __builtin_amdgcn_mfma_f32_32x32x16_bf16(afA[cur], bfA[cur][0], acc[0], 0, 0, 0);
      acc[1] = __builtin_amdgcn_mfma_f32_32x32x16_bf16(afA[cur], bfA[cur][1], acc[1], 0, 0, 0);
    }
    if (half == 0) __syncthreads();   // protect h1s before half-1 overwrites
  }

  // ---- epilogue: relu(h2+b2) . W3, reduce over k2 (32 lanes), then 4 w-waves
  float pr[16];
  #pragma unroll
  for (int reg = 0; reg < 16; ++reg) {
    float s = 0.f;
    #pragma unroll
    for (int nt = 0; nt < 2; ++nt) {
      float v = acc[nt][reg] + b2v[nt];
      v = v > 0.f ? v : 0.f;
      s += v * w3v[nt];
    }
    s += __shfl_xor(s, 1);
    s += __shfl_xor(s, 2);
    s += __shfl_xor(s, 4);
    s += __shfl_xor(s, 8);
    s += __shfl_xor(s, 16);
    pr[reg] = s;
  }
  if (c32 == 0) {
    // j_rel = jh*32 + (reg&3) + 8*(reg>>2) + 4*L
    #pragma unroll
    for (int g = 0; g < 4; ++g) {
      float4 vv = {pr[g * 4 + 0], pr[g * 4 + 1], pr[g * 4 + 2], pr[g * 4 + 3]};
      *(float4*)&red[w * 64 + jh * 32 + g * 8 + L * 4] = vv;
    }
  }
  __syncthreads();
  if (tid < 64) {
    int j = tid;
    float logit = red[j] + red[64 + j] + red[128 + j] + red[192 + j] + b3[0];
    float mm = motif[b * 256 + i] * motif[b * 256 + jbase + j];
    logit *= mm;
    float map = 1.f / (1.f + expf(-logit));
    size_t idx = (size_t)(b * 256 + i) * 256 + jbase + j;
    out[idx] = map;                           // contact_map
    out[(size_t)NB * NN * NN + idx] = logit;  // contact_logits
  }
}

// ---------------------------------------------------------------------------
extern "C" void kernel_launch(void* const* d_in, const int* in_sizes, int n_in,
                              void* d_out, int out_size, void* d_ws, size_t ws_size,
                              hipStream_t stream) {
  const float* z     = (const float*)d_in[0];
  const float* motif = (const float*)d_in[1];
  // d_in[2] residue_mask: all-ones, unused by the reference computation
  const float* W1 = (const float*)d_in[3];
  const float* b1 = (const float*)d_in[4];
  const float* W2 = (const float*)d_in[5];
  const float* b2 = (const float*)d_in[6];
  const float* W3 = (const float*)d_in[7];
  const float* b3 = (const float*)d_in[8];
  float* out = (float*)d_out;

  char* ws = (char*)d_ws;
  unsigned short* Tall = (unsigned short*)ws;                       // 32 MiB
  unsigned short* W2F  = (unsigned short*)(ws + 33554432);          // 256 KiB
  unsigned short* zbf  = (unsigned short*)(ws + 33554432 + 262144); // 64 KiB
  unsigned short* W1F  = (unsigned short*)(ws + 33554432 + 262144 + 65536); // 1 MiB

  prep_all<<<384, 256, 0, stream>>>(z, W1, W2, (unsigned*)zbf, W2F, W1F);
  prep_T2<<<dim3(64, 16), 256, 0, stream>>>(zbf, W1F, Tall);
  fused<<<4096, 512, 0, stream>>>(Tall, W2F, zbf, b1, b2, W3, b3, motif, out);
}

// Round 9
// 180.863 us; speedup vs baseline: 1.0635x; 1.0635x over previous
//
#include <hip/hip_runtime.h>
#include <hip/hip_bf16.h>
#include <cstdint>
#include <cstddef>

// Problem constants (B=4, N=256, D=32, H=512)
#define NB 4
#define NN 256
#define DD 32
#define HH 512

typedef __attribute__((ext_vector_type(8))) short short8;    // 8 bf16 (4 VGPRs) — MFMA A/B frag
typedef __attribute__((ext_vector_type(4))) float f32x4;     // 16x16 C/D frag
typedef __attribute__((ext_vector_type(16))) float f32x16;   // 32x32 C/D frag

// HW packed fp32->bf16 (RNE). a -> low 16, b -> high 16.
static __device__ __forceinline__ unsigned cvtpk(float a, float b) {
  unsigned r;
  asm("v_cvt_pk_bf16_f32 %0, %1, %2" : "=v"(r) : "v"(a), "v"(b));
  return r;
}
static __device__ __forceinline__ unsigned short f2bf1(float a) {
  return (unsigned short)(cvtpk(a, 0.f) & 0xffffu);
}

// build a bf16 A/B frag from 8 consecutive fp32 (two float4 loads already done)
static __device__ __forceinline__ short8 pack8(float4 a0, float4 a1) {
  union { unsigned u[4]; short8 s; } r;
  r.u[0] = cvtpk(a0.x, a0.y); r.u[1] = cvtpk(a0.z, a0.w);
  r.u[2] = cvtpk(a1.x, a1.y); r.u[3] = cvtpk(a1.z, a1.w);
  return r.s;
}

// ---------------------------------------------------------------------------
// prep (grid 576x256): one kernel replaces prep_all + prep_T2.
//  blk < 512 : T-GEMM. blk = nblk*8 + mgrp. Block stages its W1 slice
//    (h-cols [8*nblk,+8), all 1024 dd-rows, fp32->bf16) into LDS in
//    16x16x32 B-frag order, then runs 2 m-blocks (64 bi each) of the
//    K=32 GEMM  Tall[bi][n] = sum_a z[bi][a] * W1[(a,c)][h],
//    n = nblk*256 + w*64 + l16*4 + nt  (column interleave so stores pack).
//    z A-frags built from fp32 z directly (no zbf).
//  blk >= 512: W2F builder — W2 (512x256) into 32x32x16 B-frag order:
//    slot f8 = w*4096 + hc*512 + s*128 + nt*64 + lane (8 bf16 each)
//    h = hc*64+s*16+(lane>>5)*8+e ; k2 = w*64+nt*32+(lane&31)
// ---------------------------------------------------------------------------
__global__ __launch_bounds__(256) void prep(const float* __restrict__ z,
                                            const float* __restrict__ W1,
                                            const float* __restrict__ W2,
                                            unsigned short* __restrict__ W2F,
                                            unsigned short* __restrict__ Tall) {
  const int blk = blockIdx.x;
  const int tid = threadIdx.x;
  if (blk < 512) {
    __shared__ unsigned short w1s[16 * 512];   // 16 frag-blocks of 512 bf16
    const int nblk = blk >> 3, mgrp = blk & 7;

    // stage W1 slice: thread handles 4 dd-rows x 8 h
    #pragma unroll
    for (int rr = 0; rr < 4; ++rr) {
      int dd = tid * 4 + rr;
      const float* src = W1 + (size_t)dd * 512 + nblk * 8;
      float4 v0 = *(const float4*)(src);
      float4 v1 = *(const float4*)(src + 4);
      float hv[8] = {v0.x, v0.y, v0.z, v0.w, v1.x, v1.y, v1.z, v1.w};
      int a = dd >> 5, c = dd & 31;
      int quad = a >> 3, e = a & 7;
      int bl16 = c >> 2, nt = c & 3;
      #pragma unroll
      for (int hh = 0; hh < 8; ++hh) {
        int w = hh >> 1, hl = hh & 1;
        int l16 = hl * 8 + bl16;
        w1s[(w * 4 + nt) * 512 + (quad * 16 + l16) * 8 + e] = f2bf1(hv[hh]);
      }
    }
    __syncthreads();

    const int w = tid >> 6, lane = tid & 63;
    const int quad = lane >> 4, l16 = lane & 15;
    short8 bfr[4];
    #pragma unroll
    for (int nt = 0; nt < 4; ++nt)
      bfr[nt] = *(const short8*)&w1s[(w * 4 + nt) * 512 + lane * 8];

    const int n0 = nblk * 256 + w * 64 + l16 * 4;
    #pragma unroll
    for (int mb = 0; mb < 2; ++mb) {
      const int bibase = (mgrp * 2 + mb) * 64;
      short8 afr[4];
      #pragma unroll
      for (int mt = 0; mt < 4; ++mt) {
        const float* zr = z + (size_t)(bibase + mt * 16 + l16) * 32 + quad * 8;
        float4 a0 = *(const float4*)(zr);
        float4 a1 = *(const float4*)(zr + 4);
        afr[mt] = pack8(a0, a1);
      }
      f32x4 d[4][4];
      #pragma unroll
      for (int mt = 0; mt < 4; ++mt)
        #pragma unroll
        for (int nt = 0; nt < 4; ++nt)
          d[mt][nt] = __builtin_amdgcn_mfma_f32_16x16x32_bf16(
              afr[mt], bfr[nt], (f32x4){0.f, 0.f, 0.f, 0.f}, 0, 0, 0);
      #pragma unroll
      for (int mt = 0; mt < 4; ++mt)
        #pragma unroll
        for (int r = 0; r < 4; ++r) {
          size_t rowoff = (size_t)(bibase + mt * 16 + quad * 4 + r) * 16384;
          uint2 p;
          p.x = cvtpk(d[mt][0][r], d[mt][1][r]);
          p.y = cvtpk(d[mt][2][r], d[mt][3][r]);
          *(uint2*)&Tall[rowoff + n0] = p;
        }
    }
  } else {
    int f8 = (blk - 512) * 256 + tid;     // frag-slot index (8 elems each)
    int lane = f8 & 63;
    int nt = (f8 >> 6) & 1, s = (f8 >> 7) & 3, hc = (f8 >> 9) & 7, w = (f8 >> 12) & 3;
    int k2 = w * 64 + nt * 32 + (lane & 31);
    int hb = hc * 64 + s * 16 + (lane >> 5) * 8;
    float v[8];
    #pragma unroll
    for (int e = 0; e < 8; ++e) v[e] = W2[(hb + e) * 256 + k2];
    uint4 p;
    p.x = cvtpk(v[0], v[1]); p.y = cvtpk(v[2], v[3]);
    p.z = cvtpk(v[4], v[5]); p.w = cvtpk(v[6], v[7]);
    ((uint4*)W2F)[f8] = p;
  }
}

// ---------------------------------------------------------------------------
// fused: block = (b,i,jt of 64 j), 256 threads / 4 waves (R6 skeleton).
// H split into 2 halves of 256:
//   phase1: 4 waves fill h1s[64j][256h] (16x16x32, b1 as C-operand)
//   phase2: 16 u-steps, 4 MFMA 32x32x16/wave/step; bf (W2F global, L2-hot)
//           prefetched 3-deep, af (LDS) 2-deep -> covers ~200cyc L2 latency.
// z-frags built from fp32 z directly (zbf eliminated).
// ---------------------------------------------------------------------------
__global__ __launch_bounds__(256) void fused(const unsigned short* __restrict__ Tall,
                                             const unsigned short* __restrict__ W2F,
                                             const float* __restrict__ z,
                                             const float* __restrict__ b1,
                                             const float* __restrict__ b2,
                                             const float* __restrict__ W3,
                                             const float* __restrict__ b3,
                                             const float* __restrict__ motif,
                                             float* __restrict__ out) {
  __shared__ unsigned short h1s[64 * 264];   // [j][h_local], stride 264
  __shared__ float red[256];

  const int tid = threadIdx.x;
  const int w = tid >> 6, lane = tid & 63;
  const int quad = lane >> 4, l16 = lane & 15;
  const int L = lane >> 5, c32 = lane & 31;

  // XCD swizzle: 4 jt-siblings of one bi land on the same XCD (bx % 8 equal)
  const int bx = blockIdx.x;
  const int jt = (bx >> 3) & 3;
  const int bi = (bx & 7) | ((bx >> 5) << 3);   // b*256 + i
  const int b = bi >> 8, i = bi & 255;
  const int jbase = jt * 64;

  // phase-1 z frags (16x16x32 B-operand) from fp32 z: [k=c=quad*8+e][n=j=l16]
  short8 zfr[4];
  #pragma unroll
  for (int nt = 0; nt < 4; ++nt) {
    const float* zr = z + (size_t)(b * 256 + jbase + nt * 16 + l16) * 32 + quad * 8;
    float4 a0 = *(const float4*)(zr);
    float4 a1 = *(const float4*)(zr + 4);
    zfr[nt] = pack8(a0, a1);
  }

  // epilogue constants: this wave owns k2 in [64w, 64w+64)
  float b2v[2], w3v[2];
  #pragma unroll
  for (int nt = 0; nt < 2; ++nt) {
    int k2 = w * 64 + nt * 32 + c32;
    b2v[nt] = b2[k2];
    w3v[nt] = W3[k2];
  }

  f32x16 acc[2][2];
  #pragma unroll
  for (int mt = 0; mt < 2; ++mt)
    #pragma unroll
    for (int nt = 0; nt < 2; ++nt)
      acc[mt][nt] = (f32x16){0.f,0.f,0.f,0.f,0.f,0.f,0.f,0.f,
                             0.f,0.f,0.f,0.f,0.f,0.f,0.f,0.f};

  const unsigned short* Tbase = Tall + (size_t)bi * 16384 + (w * 16 + l16) * 32 + quad * 8;
  const unsigned short* Wp = W2F + w * 32768 + lane * 8;
  const float* b1base = b1 + w * 16 + quad * 4;

  #pragma unroll
  for (int half = 0; half < 2; ++half) {
    // ---- phase 1: wave w fills h-rows {q*64 + w*16 + [0,16)} x 64 j
    short8 tfr[4];
    #pragma unroll
    for (int q = 0; q < 4; ++q)
      tfr[q] = *(const short8*)(Tbase + (half * 4 + q) * 2048);
    #pragma unroll
    for (int q = 0; q < 4; ++q) {
      float4 b1f = *(const float4*)(b1base + (half * 4 + q) * 64);
      f32x4 cin = {b1f.x, b1f.y, b1f.z, b1f.w};
      #pragma unroll
      for (int nt = 0; nt < 4; ++nt) {
        f32x4 d = __builtin_amdgcn_mfma_f32_16x16x32_bf16(tfr[q], zfr[nt], cin, 0, 0, 0);
        // D: row = quad*4+r -> h_rel, col = l16 -> j within nt's 16
        uint2 p;
        p.x = cvtpk(fmaxf(d[0], 0.f), fmaxf(d[1], 0.f));
        p.y = cvtpk(fmaxf(d[2], 0.f), fmaxf(d[3], 0.f));
        *(uint2*)&h1s[(nt * 16 + l16) * 264 + q * 64 + w * 16 + quad * 4] = p;
      }
    }
    __syncthreads();

    // ---- phase 2: 16 u-steps (h_local = u*16 + L*8); bf 3-deep, af 2-deep
    const unsigned short* Wh = Wp + half * 16384;
    const unsigned short* h1r = &h1s[c32 * 264 + L * 8];
    short8 bfp[3][2], afp[2][2];
    #pragma unroll
    for (int p = 0; p < 3; ++p) {
      bfp[p][0] = *(const short8*)(Wh + p * 1024);
      bfp[p][1] = *(const short8*)(Wh + p * 1024 + 512);
    }
    afp[0][0] = *(const short8*)(h1r);
    afp[0][1] = *(const short8*)(h1r + 32 * 264);
    afp[1][0] = *(const short8*)(h1r + 16);
    afp[1][1] = *(const short8*)(h1r + 32 * 264 + 16);
    #pragma unroll
    for (int u = 0; u < 16; ++u) {
      const int cur = u & 1, bq = u % 3;
      short8 a0 = afp[cur][0], a1 = afp[cur][1];
      short8 b0 = bfp[bq][0], b1q = bfp[bq][1];
      if (u < 14) {
        afp[cur][0] = *(const short8*)(h1r + (u + 2) * 16);
        afp[cur][1] = *(const short8*)(h1r + 32 * 264 + (u + 2) * 16);
      }
      if (u < 13) {
        bfp[bq][0] = *(const short8*)(Wh + (u + 3) * 1024);
        bfp[bq][1] = *(const short8*)(Wh + (u + 3) * 1024 + 512);
      }
      acc[0][0] = __builtin_amdgcn_mfma_f32_32x32x16_bf16(a0, b0, acc[0][0], 0, 0, 0);
      acc[0][1] = __builtin_amdgcn_mfma_f32_32x32x16_bf16(a0, b1q, acc[0][1], 0, 0, 0);
      acc[1][0] = __builtin_amdgcn_mfma_f32_32x32x16_bf16(a1, b0, acc[1][0], 0, 0, 0);
      acc[1][1] = __builtin_amdgcn_mfma_f32_32x32x16_bf16(a1, b1q, acc[1][1], 0, 0, 0);
    }
    if (half == 0) __syncthreads();   // protect h1s before half-1 overwrites
  }

  // ---- epilogue: relu(h2+b2) . W3, reduce over k2 (32 lanes), then 4 waves
  float pr[2][16];
  #pragma unroll
  for (int mt = 0; mt < 2; ++mt)
    #pragma unroll
    for (int reg = 0; reg < 16; ++reg) {
      float s = 0.f;
      #pragma unroll
      for (int nt = 0; nt < 2; ++nt) {
        float v = acc[mt][nt][reg] + b2v[nt];
        v = v > 0.f ? v : 0.f;
        s += v * w3v[nt];
      }
      s += __shfl_xor(s, 1);
      s += __shfl_xor(s, 2);
      s += __shfl_xor(s, 4);
      s += __shfl_xor(s, 8);
      s += __shfl_xor(s, 16);
      pr[mt][reg] = s;
    }
  if (c32 == 0) {
    #pragma unroll
    for (int mt = 0; mt < 2; ++mt)
      #pragma unroll
      for (int g = 0; g < 4; ++g) {
        float4 vv = {pr[mt][g * 4 + 0], pr[mt][g * 4 + 1],
                     pr[mt][g * 4 + 2], pr[mt][g * 4 + 3]};
        // j_rel = mt*32 + 8g + 4L + r
        *(float4*)&red[w * 64 + mt * 32 + g * 8 + L * 4] = vv;
      }
  }
  __syncthreads();
  if (tid < 64) {
    int j = tid;
    float logit = red[j] + red[64 + j] + red[128 + j] + red[192 + j] + b3[0];
    float mm = motif[b * 256 + i] * motif[b * 256 + jbase + j];
    logit *= mm;
    float map = 1.f / (1.f + expf(-logit));
    size_t idx = (size_t)(b * 256 + i) * 256 + jbase + j;
    out[idx] = map;                           // contact_map
    out[(size_t)NB * NN * NN + idx] = logit;  // contact_logits
  }
}

// ---------------------------------------------------------------------------
extern "C" void kernel_launch(void* const* d_in, const int* in_sizes, int n_in,
                              void* d_out, int out_size, void* d_ws, size_t ws_size,
                              hipStream_t stream) {
  const float* z     = (const float*)d_in[0];
  const float* motif = (const float*)d_in[1];
  // d_in[2] residue_mask: all-ones, unused by the reference computation
  const float* W1 = (const float*)d_in[3];
  const float* b1 = (const float*)d_in[4];
  const float* W2 = (const float*)d_in[5];
  const float* b2 = (const float*)d_in[6];
  const float* W3 = (const float*)d_in[7];
  const float* b3 = (const float*)d_in[8];
  float* out = (float*)d_out;

  char* ws = (char*)d_ws;
  unsigned short* Tall = (unsigned short*)ws;                       // 32 MiB
  unsigned short* W2F  = (unsigned short*)(ws + 33554432);          // 256 KiB

  prep<<<576, 256, 0, stream>>>(z, W1, W2, W2F, Tall);
  fused<<<4096, 256, 0, stream>>>(Tall, W2F, z, b1, b2, W3, b3, motif, out);
}